// Round 2
// baseline (314.811 us; speedup 1.0000x reference)
//
#include <hip/hip_runtime.h>
#include <hip/hip_bf16.h>

// Problem constants (fixed by the reference)
static constexpr int Bc   = 8;
static constexpr int Nn   = 24576;
static constexpr int Kk   = 16;
static constexpr int Cc   = 64;          // C_IN == C_OUT == 64
static constexpr int Rr   = Bc * Nn;     // 196608 total rows
static constexpr float EPS = 1e-5f;

// ---------------------------------------------------------------------------
// K1: h[r][o] = sum_c x[r][c] * W[o][c]
// lane = o (64 output channels). W row held in 64 VGPRs per lane.
// x rows staged in LDS, broadcast-read (same address across lanes -> free).
// Block 256 = 4 waves; 16 rows staged per iteration; each wave computes 4 rows.
// ---------------------------------------------------------------------------
__global__ __launch_bounds__(256) void linear_kernel(
    const float* __restrict__ x, const float* __restrict__ W,
    float* __restrict__ h)
{
    __shared__ float xs[16][64];
    const int tid  = threadIdx.x;
    const int lane = tid & 63;
    const int wave = tid >> 6;

    float w[64];
#pragma unroll
    for (int c4 = 0; c4 < 16; ++c4) {
        float4 t = *reinterpret_cast<const float4*>(&W[lane * 64 + c4 * 4]);
        w[c4 * 4 + 0] = t.x; w[c4 * 4 + 1] = t.y;
        w[c4 * 4 + 2] = t.z; w[c4 * 4 + 3] = t.w;
    }

    const int ntiles = Rr / 16;  // 12288
    for (int tile = blockIdx.x; tile < ntiles; tile += gridDim.x) {
        const int row0 = tile * 16;
        // stage 16 rows (4 KB): 256 threads x 16 B
        reinterpret_cast<float4*>(&xs[0][0])[tid] =
            reinterpret_cast<const float4*>(&x[row0 * 64])[tid];
        __syncthreads();
#pragma unroll
        for (int rr = 0; rr < 4; ++rr) {
            const int r = wave * 4 + rr;
            float acc = 0.f;
#pragma unroll
            for (int c = 0; c < 64; ++c)
                acc = fmaf(xs[r][c], w[c], acc);
            h[(row0 + r) * 64 + lane] = acc;
        }
        __syncthreads();
    }
}

// ---------------------------------------------------------------------------
// K2: v[r][o] = (max_k h[nbr(r,k)][o]) - h[r][o]; writes v into d_out.
// Accumulates per-channel sum / sumsq partials -> block LDS reduce -> atomicAdd.
// lane = channel. Neighbor indices are wave-uniform -> __shfl broadcast.
// ---------------------------------------------------------------------------
__global__ __launch_bounds__(256) void gather_bn_kernel(
    const float* __restrict__ h, const int* __restrict__ knn,
    float* __restrict__ v, float* __restrict__ stats)
{
    const int tid   = threadIdx.x;
    const int lane  = tid & 63;
    const int wave  = tid >> 6;
    const int gwave = blockIdx.x * 4 + wave;
    const int nwav  = gridDim.x * 4;

    float lsum = 0.f, lsq = 0.f;

    for (int row = gwave; row < Rr; row += nwav) {
        const int b     = row / Nn;          // constant divisor -> magic mul
        const int bbase = b * Nn;
        const int idx   = knn[row * Kk + (lane & 15)];
        const float hown = h[row * 64 + lane];
        float m = -1e30f;
#pragma unroll
        for (int k = 0; k < Kk; ++k) {
            const int j = __shfl(idx, k);
            m = fmaxf(m, h[(bbase + j) * 64 + lane]);
        }
        const float val = m - hown;
        v[row * 64 + lane] = val;
        lsum += val;
        lsq  += val * val;
    }

    __shared__ float s_sum[4][64];
    __shared__ float s_sq[4][64];
    s_sum[wave][lane] = lsum;
    s_sq[wave][lane]  = lsq;
    __syncthreads();
    if (wave == 0) {
        const float a = s_sum[0][lane] + s_sum[1][lane] + s_sum[2][lane] + s_sum[3][lane];
        const float q = s_sq[0][lane]  + s_sq[1][lane]  + s_sq[2][lane]  + s_sq[3][lane];
        atomicAdd(&stats[lane], a);
        atomicAdd(&stats[64 + lane], q);
    }
}

// ---------------------------------------------------------------------------
// K3: finalize BN stats -> scale/shift (one 64-thread block)
// ---------------------------------------------------------------------------
__global__ __launch_bounds__(64) void finalize_stats_kernel(
    const float* __restrict__ stats, const float* __restrict__ gamma,
    const float* __restrict__ beta, float* __restrict__ ss)
{
    const int o = threadIdx.x;
    const float inv_count = 1.0f / (float)Rr;
    const float mean = stats[o] * inv_count;
    const float var  = stats[64 + o] * inv_count - mean * mean;
    const float sc   = gamma[o] * rsqrtf(var + EPS);
    ss[o]      = sc;
    ss[64 + o] = beta[o] - mean * sc;
}

// ---------------------------------------------------------------------------
// K4: in-place normalize d_out: out = v*scale[c] + shift[c], float4 stream
// ---------------------------------------------------------------------------
__global__ __launch_bounds__(256) void norm_kernel(
    float* __restrict__ v, const float* __restrict__ ss)
{
    __shared__ float sc[64], sh[64];
    if (threadIdx.x < 64) {
        sc[threadIdx.x] = ss[threadIdx.x];
        sh[threadIdx.x] = ss[64 + threadIdx.x];
    }
    __syncthreads();

    const int total4 = Rr * 64 / 4;  // 3,145,728 float4s
    for (int i = blockIdx.x * blockDim.x + threadIdx.x; i < total4;
         i += gridDim.x * blockDim.x) {
        float4 t = reinterpret_cast<float4*>(v)[i];
        const int c = (i * 4) & 63;
        t.x = t.x * sc[c + 0] + sh[c + 0];
        t.y = t.y * sc[c + 1] + sh[c + 1];
        t.z = t.z * sc[c + 2] + sh[c + 2];
        t.w = t.w * sc[c + 3] + sh[c + 3];
        reinterpret_cast<float4*>(v)[i] = t;
    }
}

// ---------------------------------------------------------------------------
extern "C" void kernel_launch(void* const* d_in, const int* in_sizes, int n_in,
                              void* d_out, int out_size, void* d_ws, size_t ws_size,
                              hipStream_t stream)
{
    const float* x     = (const float*)d_in[0];
    const float* W     = (const float*)d_in[1];
    const float* gamma = (const float*)d_in[2];
    const float* beta  = (const float*)d_in[3];
    const int*   knn   = (const int*)d_in[4];
    float*       out   = (float*)d_out;

    // workspace layout: h [Rr*64 floats] | stats [128] | scale_shift [128]
    float* h     = (float*)d_ws;
    float* stats = h + (size_t)Rr * 64;
    float* ss    = stats + 128;

    // zero the stats accumulators (ws is poisoned each call)
    hipMemsetAsync(stats, 0, 128 * sizeof(float), stream);

    linear_kernel<<<12288, 256, 0, stream>>>(x, W, h);
    gather_bn_kernel<<<1536, 256, 0, stream>>>(h, knn, out, stats);
    finalize_stats_kernel<<<1, 64, 0, stream>>>(stats, gamma, beta, ss);
    norm_kernel<<<2048, 256, 0, stream>>>(out, ss);
}

// Round 3
// 237.770 us; speedup vs baseline: 1.3240x; 1.3240x over previous
//
#include <hip/hip_runtime.h>
#include <hip/hip_bf16.h>

// Problem constants (fixed by the reference)
static constexpr int Bc   = 8;
static constexpr int Nn   = 24576;
static constexpr int Kk   = 16;
static constexpr int Cc   = 64;          // C_IN == C_OUT == 64
static constexpr int Rr   = Bc * Nn;     // 196608 total rows
static constexpr float EPS = 1e-5f;

// ---------------------------------------------------------------------------
// K1: h[r][o] = sum_c x[r][c] * W[o][c], stored as bf16.
// lane = o. W row in 64 VGPRs/lane. x rows staged in LDS, broadcast float4
// reads (ds_read_b128, same-address broadcast = conflict-free).
// grid 1024 -> each block loops ~12 tiles; W loaded once per block.
// ---------------------------------------------------------------------------
__global__ __launch_bounds__(256) void linear_kernel(
    const float* __restrict__ x, const float* __restrict__ W,
    __hip_bfloat16* __restrict__ h)
{
    __shared__ float xs[16][64];
    const int tid  = threadIdx.x;
    const int lane = tid & 63;
    const int wave = tid >> 6;

    float w[64];
#pragma unroll
    for (int c4 = 0; c4 < 16; ++c4) {
        float4 t = *reinterpret_cast<const float4*>(&W[lane * 64 + c4 * 4]);
        w[c4 * 4 + 0] = t.x; w[c4 * 4 + 1] = t.y;
        w[c4 * 4 + 2] = t.z; w[c4 * 4 + 3] = t.w;
    }

    const int ntiles = Rr / 16;  // 12288
    for (int tile = blockIdx.x; tile < ntiles; tile += gridDim.x) {
        const int row0 = tile * 16;
        reinterpret_cast<float4*>(&xs[0][0])[tid] =
            reinterpret_cast<const float4*>(&x[row0 * 64])[tid];
        __syncthreads();
#pragma unroll
        for (int rr = 0; rr < 4; ++rr) {
            const int r = wave * 4 + rr;
            float acc = 0.f;
#pragma unroll
            for (int c4 = 0; c4 < 16; ++c4) {
                float4 t = *reinterpret_cast<const float4*>(&xs[r][c4 * 4]);
                acc = fmaf(t.x, w[c4 * 4 + 0], acc);
                acc = fmaf(t.y, w[c4 * 4 + 1], acc);
                acc = fmaf(t.z, w[c4 * 4 + 2], acc);
                acc = fmaf(t.w, w[c4 * 4 + 3], acc);
            }
            h[(row0 + r) * 64 + lane] = __float2bfloat16(acc);
        }
        __syncthreads();
    }
}

// ---------------------------------------------------------------------------
// K2: v[r][o] = (max_k h_bf16[nbr(r,k)][o]) - h_bf16[r][o]  (fp32 math),
// writes v (fp32) into d_out, accumulates per-channel sum/sumsq ->
// LDS reduce -> atomicAdd. One batch's h slice = 3 MB bf16 -> fits 4 MB
// per-XCD L2; grid-stride window keeps one batch hot at a time.
// ---------------------------------------------------------------------------
__global__ __launch_bounds__(256) void gather_bn_kernel(
    const __hip_bfloat16* __restrict__ h, const int* __restrict__ knn,
    float* __restrict__ v, float* __restrict__ stats)
{
    const int tid   = threadIdx.x;
    const int lane  = tid & 63;
    const int wave  = tid >> 6;
    const int gwave = blockIdx.x * 4 + wave;
    const int nwav  = gridDim.x * 4;

    float lsum = 0.f, lsq = 0.f;

    for (int row = gwave; row < Rr; row += nwav) {
        const int b     = row / Nn;          // constant divisor -> magic mul
        const int bbase = b * Nn;
        const int idx   = knn[row * Kk + (lane & 15)];
        const float hown = __bfloat162float(h[row * 64 + lane]);
        float m = -1e30f;
#pragma unroll
        for (int k = 0; k < Kk; ++k) {
            const int j = __shfl(idx, k);
            m = fmaxf(m, __bfloat162float(h[(bbase + j) * 64 + lane]));
        }
        const float val = m - hown;
        v[row * 64 + lane] = val;
        lsum += val;
        lsq  += val * val;
    }

    __shared__ float s_sum[4][64];
    __shared__ float s_sq[4][64];
    s_sum[wave][lane] = lsum;
    s_sq[wave][lane]  = lsq;
    __syncthreads();
    if (wave == 0) {
        const float a = s_sum[0][lane] + s_sum[1][lane] + s_sum[2][lane] + s_sum[3][lane];
        const float q = s_sq[0][lane]  + s_sq[1][lane]  + s_sq[2][lane]  + s_sq[3][lane];
        atomicAdd(&stats[lane], a);
        atomicAdd(&stats[64 + lane], q);
    }
}

// ---------------------------------------------------------------------------
// K3: finalize BN stats -> scale/shift (one 64-thread block)
// ---------------------------------------------------------------------------
__global__ __launch_bounds__(64) void finalize_stats_kernel(
    const float* __restrict__ stats, const float* __restrict__ gamma,
    const float* __restrict__ beta, float* __restrict__ ss)
{
    const int o = threadIdx.x;
    const float inv_count = 1.0f / (float)Rr;
    const float mean = stats[o] * inv_count;
    const float var  = stats[64 + o] * inv_count - mean * mean;
    const float sc   = gamma[o] * rsqrtf(var + EPS);
    ss[o]      = sc;
    ss[64 + o] = beta[o] - mean * sc;
}

// ---------------------------------------------------------------------------
// K4: in-place normalize d_out: out = v*scale[c] + shift[c], float4 stream
// ---------------------------------------------------------------------------
__global__ __launch_bounds__(256) void norm_kernel(
    float* __restrict__ v, const float* __restrict__ ss)
{
    __shared__ float sc[64], sh[64];
    if (threadIdx.x < 64) {
        sc[threadIdx.x] = ss[threadIdx.x];
        sh[threadIdx.x] = ss[64 + threadIdx.x];
    }
    __syncthreads();

    const int total4 = Rr * 64 / 4;  // 3,145,728 float4s
    for (int i = blockIdx.x * blockDim.x + threadIdx.x; i < total4;
         i += gridDim.x * blockDim.x) {
        float4 t = reinterpret_cast<float4*>(v)[i];
        const int c = (i * 4) & 63;
        t.x = t.x * sc[c + 0] + sh[c + 0];
        t.y = t.y * sc[c + 1] + sh[c + 1];
        t.z = t.z * sc[c + 2] + sh[c + 2];
        t.w = t.w * sc[c + 3] + sh[c + 3];
        reinterpret_cast<float4*>(v)[i] = t;
    }
}

// ---------------------------------------------------------------------------
extern "C" void kernel_launch(void* const* d_in, const int* in_sizes, int n_in,
                              void* d_out, int out_size, void* d_ws, size_t ws_size,
                              hipStream_t stream)
{
    const float* x     = (const float*)d_in[0];
    const float* W     = (const float*)d_in[1];
    const float* gamma = (const float*)d_in[2];
    const float* beta  = (const float*)d_in[3];
    const int*   knn   = (const int*)d_in[4];
    float*       out   = (float*)d_out;

    // workspace layout: h_bf16 [Rr*64] | stats [128 f32] | scale_shift [128 f32]
    __hip_bfloat16* h = (__hip_bfloat16*)d_ws;
    float* stats = (float*)((char*)d_ws + (size_t)Rr * 64 * sizeof(__hip_bfloat16));
    float* ss    = stats + 128;

    hipMemsetAsync(stats, 0, 128 * sizeof(float), stream);

    linear_kernel<<<1024, 256, 0, stream>>>(x, W, h);
    gather_bn_kernel<<<2048, 256, 0, stream>>>(h, knn, out, stats);
    finalize_stats_kernel<<<1, 64, 0, stream>>>(stats, gamma, beta, ss);
    norm_kernel<<<2048, 256, 0, stream>>>(out, ss);
}